// Round 3
// baseline (1099.287 us; speedup 1.0000x reference)
//
#include <hip/hip_runtime.h>
#include <hip/hip_cooperative_groups.h>
#include <math.h>

namespace cg = cooperative_groups;

#define N_NODES 4096
#define IN_DIM  1433
#define HID     64
#define OUT_DIM 7
#define FPAD    8       // padded feature stride for vectorized gathers
#define CAP     128     // max neighbors per node (avg 32, sigma 5.6; 128 >15 sigma)
#define KSPLIT  8
#define BR      32      // rows per gemm1 block (32 -> 1024 blocks = 4/CU)
#define KT      32      // k-tile

static constexpr float LAMBDA = (float)(1.0 / 0.9 - 1.0);   // 0.11111111
static constexpr float SCADA  = 3.7f;

// ---------------------------------------------------------------------------
// Kernel 1: extract sparse adjacency + degrees from dense binary A (zero diag)
// ---------------------------------------------------------------------------
__global__ __launch_bounds__(256) void build_adj(const float* __restrict__ A,
    int* __restrict__ nbr, int* __restrict__ cnt, float* __restrict__ deg,
    float* __restrict__ rsd) {
  int i = blockIdx.x;
  __shared__ int c;
  if (threadIdx.x == 0) c = 0;
  __syncthreads();
  const float4* row = (const float4*)(A + (size_t)i * N_NODES);
  for (int q = threadIdx.x; q < N_NODES / 4; q += 256) {
    float4 v = row[q];
    int j0 = q * 4;
    if (v.x != 0.0f) { int s = atomicAdd(&c, 1); if (s < CAP) nbr[(size_t)i * CAP + s] = j0; }
    if (v.y != 0.0f) { int s = atomicAdd(&c, 1); if (s < CAP) nbr[(size_t)i * CAP + s] = j0 + 1; }
    if (v.z != 0.0f) { int s = atomicAdd(&c, 1); if (s < CAP) nbr[(size_t)i * CAP + s] = j0 + 2; }
    if (v.w != 0.0f) { int s = atomicAdd(&c, 1); if (s < CAP) nbr[(size_t)i * CAP + s] = j0 + 3; }
  }
  __syncthreads();
  if (threadIdx.x == 0) {
    int cc = c; if (cc > CAP) cc = CAP;
    cnt[i] = cc;
    float d = (float)c + 1.0f;      // + self loop
    deg[i] = d;
    rsd[i] = 1.0f / sqrtf(d);
  }
}

// ---------------------------------------------------------------------------
// Kernel 2: P[ks] = X[:, kchunk] @ w1[kchunk, :]  (split-K partials)
// 1024 blocks (4/CU). Register-prefetch pipeline: next tile is loaded into
// VGPRs before computing the current LDS tile, so vmcnt waits land after
// ~512 cycles of FMA. Single LDS buffer, 2 barriers per tile.
// ---------------------------------------------------------------------------
__global__ __launch_bounds__(256) void gemm1(const float* __restrict__ X,
    const float* __restrict__ w1, float* __restrict__ P) {
  __shared__ __align__(16) float Xs[KT][BR + 4];   // 32x36 words (b64-aligned rows)
  __shared__ __align__(16) float Ws[KT][HID];      // 32x64
  const int t  = threadIdx.x;
  const int r0 = blockIdx.x * BR;
  const int ks = blockIdx.y;
  const int kbeg = (IN_DIM * ks) / KSPLIT;
  const int kend = (IN_DIM * (ks + 1)) / KSPLIT;
  const int ntile = (kend - kbeg + KT - 1) / KT;   // 6
  const int rg = t >> 4;    // 0..15 -> rows rg*2, rg*2+1
  const int cg = t & 15;    // cols cg*4 .. cg*4+3

  float xp[4], wp[8];   // prefetch registers
  #pragma unroll
  for (int j = 0; j < 4; ++j) {            // X: e=t+256j, row=e>>5, kk=e&31 (coalesced)
    int e = t + 256 * j; int k = kbeg + (e & 31);
    xp[j] = (k < kend) ? X[(size_t)(r0 + (e >> 5)) * IN_DIM + k] : 0.0f;
  }
  #pragma unroll
  for (int j = 0; j < 8; ++j) {            // W: e=t+256j, kk=e>>6, col=e&63 (coalesced)
    int e = t + 256 * j; int k = kbeg + (e >> 6);
    wp[j] = (k < kend) ? w1[(size_t)k * HID + (e & 63)] : 0.0f;
  }

  float acc[2][4] = {};
  for (int tile = 0; tile < ntile; ++tile) {
    #pragma unroll
    for (int j = 0; j < 4; ++j) { int e = t + 256 * j; Xs[e & 31][e >> 5] = xp[j]; }
    #pragma unroll
    for (int j = 0; j < 8; ++j) { int e = t + 256 * j; Ws[e >> 6][e & 63] = wp[j]; }
    __syncthreads();
    if (tile + 1 < ntile) {                // prefetch next tile (latency hidden by FMA below)
      int kn = kbeg + (tile + 1) * KT;
      #pragma unroll
      for (int j = 0; j < 4; ++j) {
        int e = t + 256 * j; int k = kn + (e & 31);
        xp[j] = (k < kend) ? X[(size_t)(r0 + (e >> 5)) * IN_DIM + k] : 0.0f;
      }
      #pragma unroll
      for (int j = 0; j < 8; ++j) {
        int e = t + 256 * j; int k = kn + (e >> 6);
        wp[j] = (k < kend) ? w1[(size_t)k * HID + (e & 63)] : 0.0f;
      }
    }
    #pragma unroll
    for (int kk = 0; kk < KT; ++kk) {
      const float2 xv = *(const float2*)&Xs[kk][rg * 2];   // 16 addrs, 2-way alias = free
      const float4 wv = *(const float4*)&Ws[kk][cg * 4];
      float xr[2] = {xv.x, xv.y};
      float wc[4] = {wv.x, wv.y, wv.z, wv.w};
      #pragma unroll
      for (int r = 0; r < 2; ++r)
        #pragma unroll
        for (int c = 0; c < 4; ++c) acc[r][c] += xr[r] * wc[c];
    }
    __syncthreads();
  }
  float* Pp = P + (size_t)ks * N_NODES * HID;
  #pragma unroll
  for (int r = 0; r < 2; ++r) {
    int row = r0 + rg * 2 + r;
    *(float4*)&Pp[(size_t)row * HID + cg * 4] =
        make_float4(acc[r][0], acc[r][1], acc[r][2], acc[r][3]);
  }
}

// ---------------------------------------------------------------------------
// Kernel 2b: H = sum over split-K partials (vectorized float4)
// ---------------------------------------------------------------------------
__global__ __launch_bounds__(256) void reduce_h(const float* __restrict__ P,
    float* __restrict__ H) {
  int idx4 = blockIdx.x * 256 + threadIdx.x;          // 65536 float4 slots
  const float4* P4 = (const float4*)P;
  float4 s = P4[idx4];
  #pragma unroll
  for (int ks = 1; ks < KSPLIT; ++ks) {
    float4 v = P4[(size_t)ks * (N_NODES * HID / 4) + idx4];
    s.x += v.x; s.y += v.y; s.z += v.z; s.w += v.w;
  }
  ((float4*)H)[idx4] = s;
}

// ---------------------------------------------------------------------------
// Kernel 3: F0 = relu(H + b1) @ w2 + b2 ; seed Fcur = F0. Padded stride 8.
// ---------------------------------------------------------------------------
__global__ __launch_bounds__(256) void mlp_out(const float* __restrict__ H,
    const float* __restrict__ b1, const float* __restrict__ w2,
    const float* __restrict__ b2, float* __restrict__ F0, float* __restrict__ Fcur) {
  int t = blockIdx.x * blockDim.x + threadIdx.x;      // N*8 threads
  if (t >= N_NODES * FPAD) return;
  int row = t >> 3, c = t & 7;
  if (c == 7) { F0[t] = 0.0f; Fcur[t] = 0.0f; return; }
  float acc = b2[c];
  const float* h = H + (size_t)row * HID;
  #pragma unroll
  for (int k = 0; k < HID; ++k) {
    float hv = fmaxf(h[k] + b1[k], 0.0f);
    acc += hv * w2[k * OUT_DIM + c];
  }
  F0[t] = acc;
  Fcur[t] = acc;
}

// ---------------------------------------------------------------------------
// Kernel 4: ALL 10 RUNG steps in one cooperative kernel (grid.sync between
// steps). One wave per node; neighbor ids + rsd[j] hoisted out of the k-loop.
// ---------------------------------------------------------------------------
__global__ __launch_bounds__(256, 4) void rung_all(
    float* __restrict__ FA, float* __restrict__ FB,
    const float* __restrict__ F0, float* __restrict__ out,
    const int* __restrict__ nbr, const int* __restrict__ cnt,
    const float* __restrict__ deg, const float* __restrict__ rsd,
    const float* __restrict__ lg0p, const float* __restrict__ rdp) {
  cg::grid_group grid = cg::this_grid();
  int wave = threadIdx.x >> 6;
  int lane = threadIdx.x & 63;
  int i = blockIdx.x * 4 + wave;

  float r_  = 1.0f / (1.0f + expf(-rdp[0]));
  float lam = expf(lg0p[0]) * (1.0f / SCADA);          // lam_0; *= r_ each step

  float rsi = rsd[i];
  float Di  = deg[i];
  int   ci  = cnt[i];
  // hoisted neighbor state: lane covers slots lane and lane+64 (CAP=128)
  int   j0 = -1, j1 = -1;
  float rsj0 = 0.0f, rsj1 = 0.0f;
  if (lane < ci)      { j0 = nbr[(size_t)i * CAP + lane];      rsj0 = rsd[j0]; }
  if (lane + 64 < ci) { j1 = nbr[(size_t)i * CAP + lane + 64]; rsj1 = rsd[j1]; }
  float lf0[OUT_DIM];
  #pragma unroll
  for (int c = 0; c < OUT_DIM; ++c) lf0[c] = LAMBDA * F0[(size_t)i * FPAD + c];

  float* Fin  = FA;
  float* Fout = FB;
  for (int k = 0; k < 10; ++k) {
    if (k) grid.sync();                  // step k-1 writes visible device-wide
    float Fni[FPAD];
    {
      const float4* fp = (const float4*)(Fin + (size_t)i * FPAD);
      float4 a0 = fp[0], a1 = fp[1];
      Fni[0] = a0.x * rsi; Fni[1] = a0.y * rsi; Fni[2] = a0.z * rsi; Fni[3] = a0.w * rsi;
      Fni[4] = a1.x * rsi; Fni[5] = a1.y * rsi; Fni[6] = a1.z * rsi; Fni[7] = a1.w * rsi;
    }
    float s = 0.0f;
    float acc[OUT_DIM] = {0, 0, 0, 0, 0, 0, 0};
    #pragma unroll
    for (int half = 0; half < 2; ++half) {
      int   j   = half ? j1 : j0;
      float rsj = half ? rsj1 : rsj0;
      if (j >= 0) {
        const float4* fp = (const float4*)(Fin + (size_t)j * FPAD);
        float4 b0 = fp[0], b1v = fp[1];
        float fj[FPAD] = {b0.x, b0.y, b0.z, b0.w, b1v.x, b1v.y, b1v.z, b1v.w};
        float d2 = 0.0f;
        #pragma unroll
        for (int c = 0; c < FPAD; ++c) {
          float df = Fni[c] - fj[c] * rsj;
          d2 += df * df;
        }
        float y = sqrtf(d2);
        float w;
        if (y <= lam)              w = 1.0f;
        else if (y <= SCADA * lam) w = (SCADA * lam - y) / ((SCADA - 1.0f) * fmaxf(y, 1e-12f));
        else                       w = 0.0f;
        if (w != w) w = 1.0f;      // NaN guard (matches reference)
        s += w;
        float wr = w * rsi * rsj;  // W_ij * A_tilde_ij
        #pragma unroll
        for (int c = 0; c < OUT_DIM; ++c) acc[c] += wr * fj[c];
      }
    }
    #pragma unroll
    for (int off = 32; off > 0; off >>= 1) {
      s += __shfl_down(s, off);
      #pragma unroll
      for (int c = 0; c < OUT_DIM; ++c) acc[c] += __shfl_down(acc[c], off);
    }
    if (lane == 0) {
      float inv = 1.0f / (s / Di + LAMBDA);
      if (k == 9) {
        #pragma unroll
        for (int c = 0; c < OUT_DIM; ++c)
          out[(size_t)i * OUT_DIM + c] = (acc[c] + lf0[c]) * inv;
      } else {
        float o[OUT_DIM];
        #pragma unroll
        for (int c = 0; c < OUT_DIM; ++c) o[c] = (acc[c] + lf0[c]) * inv;
        float4* op = (float4*)(Fout + (size_t)i * FPAD);
        op[0] = make_float4(o[0], o[1], o[2], o[3]);
        op[1] = make_float4(o[4], o[5], o[6], 0.0f);
      }
    }
    lam *= r_;
    float* tmp = Fin; Fin = Fout; Fout = tmp;
  }
}

// ---------------------------------------------------------------------------
extern "C" void kernel_launch(void* const* d_in, const int* in_sizes, int n_in,
                              void* d_out, int out_size, void* d_ws, size_t ws_size,
                              hipStream_t stream) {
  const float* A   = (const float*)d_in[0];
  const float* X   = (const float*)d_in[1];
  const float* w1  = (const float*)d_in[2];
  const float* b1  = (const float*)d_in[3];
  const float* w2  = (const float*)d_in[4];
  const float* b2  = (const float*)d_in[5];
  const float* lg0 = (const float*)d_in[6];
  const float* rd  = (const float*)d_in[7];
  float* out = (float*)d_out;

  char* w = (char*)d_ws;
  int*   nbr = (int*)w;   w += (size_t)N_NODES * CAP * sizeof(int);
  int*   cnt = (int*)w;   w += (size_t)N_NODES * sizeof(int);
  float* deg = (float*)w; w += (size_t)N_NODES * sizeof(float);
  float* rsd = (float*)w; w += (size_t)N_NODES * sizeof(float);
  float* P   = (float*)w; w += (size_t)KSPLIT * N_NODES * HID * sizeof(float);
  float* H   = (float*)w; w += (size_t)N_NODES * HID * sizeof(float);
  float* F0  = (float*)w; w += (size_t)N_NODES * FPAD * sizeof(float);
  float* FA  = (float*)w; w += (size_t)N_NODES * FPAD * sizeof(float);
  float* FB  = (float*)w; w += (size_t)N_NODES * FPAD * sizeof(float);

  build_adj<<<N_NODES, 256, 0, stream>>>(A, nbr, cnt, deg, rsd);
  gemm1<<<dim3(N_NODES / BR, KSPLIT), 256, 0, stream>>>(X, w1, P);
  reduce_h<<<(N_NODES * HID / 4) / 256, 256, 0, stream>>>(P, H);
  mlp_out<<<(N_NODES * FPAD) / 256, 256, 0, stream>>>(H, b1, w2, b2, F0, FA);

  void* args[] = {&FA, &FB, &F0, &out, &nbr, &cnt, &deg, &rsd,
                  (void*)&lg0, (void*)&rd};
  hipLaunchCooperativeKernel((const void*)rung_all, dim3(N_NODES / 4), dim3(256),
                             args, 0, stream);
}

// Round 4
// 373.749 us; speedup vs baseline: 2.9412x; 2.9412x over previous
//
#include <hip/hip_runtime.h>
#include <math.h>

#define N_NODES 4096
#define IN_DIM  1433
#define HID     64
#define OUT_DIM 7
#define FPAD    8       // padded feature stride for vectorized gathers
#define CAP     128     // max neighbors per node (avg 32, sigma 5.6; 128 >15 sigma)
#define KSPLIT  8
#define BR      32      // rows per gemm1 block (32 -> 1024 blocks = 4/CU)
#define KT      32      // k-tile
#define RB      256     // rung blocks (1/CU; barrier participants)
#define RT      1024    // rung threads per block (16 waves)

static constexpr float LAMBDA = (float)(1.0 / 0.9 - 1.0);   // 0.11111111
static constexpr float SCADA  = 3.7f;

// ---------------------------------------------------------------------------
// Kernel 1: extract sparse adjacency + degrees from dense binary A (zero diag)
// ---------------------------------------------------------------------------
__global__ __launch_bounds__(256) void build_adj(const float* __restrict__ A,
    int* __restrict__ nbr, int* __restrict__ cnt, float* __restrict__ deg,
    float* __restrict__ rsd) {
  int i = blockIdx.x;
  __shared__ int c;
  if (threadIdx.x == 0) c = 0;
  __syncthreads();
  const float4* row = (const float4*)(A + (size_t)i * N_NODES);
  for (int q = threadIdx.x; q < N_NODES / 4; q += 256) {
    float4 v = row[q];
    int j0 = q * 4;
    if (v.x != 0.0f) { int s = atomicAdd(&c, 1); if (s < CAP) nbr[(size_t)i * CAP + s] = j0; }
    if (v.y != 0.0f) { int s = atomicAdd(&c, 1); if (s < CAP) nbr[(size_t)i * CAP + s] = j0 + 1; }
    if (v.z != 0.0f) { int s = atomicAdd(&c, 1); if (s < CAP) nbr[(size_t)i * CAP + s] = j0 + 2; }
    if (v.w != 0.0f) { int s = atomicAdd(&c, 1); if (s < CAP) nbr[(size_t)i * CAP + s] = j0 + 3; }
  }
  __syncthreads();
  if (threadIdx.x == 0) {
    int cc = c; if (cc > CAP) cc = CAP;
    cnt[i] = cc;
    float d = (float)c + 1.0f;      // + self loop
    deg[i] = d;
    rsd[i] = 1.0f / sqrtf(d);
  }
}

// ---------------------------------------------------------------------------
// Kernel 2: P[ks] = X[:, kchunk] @ w1[kchunk, :]  (split-K partials)
// 1024 blocks (4/CU), register-prefetch pipeline, single LDS buffer.
// ---------------------------------------------------------------------------
__global__ __launch_bounds__(256) void gemm1(const float* __restrict__ X,
    const float* __restrict__ w1, float* __restrict__ P) {
  __shared__ __align__(16) float Xs[KT][BR + 4];
  __shared__ __align__(16) float Ws[KT][HID];
  const int t  = threadIdx.x;
  const int r0 = blockIdx.x * BR;
  const int ks = blockIdx.y;
  const int kbeg = (IN_DIM * ks) / KSPLIT;
  const int kend = (IN_DIM * (ks + 1)) / KSPLIT;
  const int ntile = (kend - kbeg + KT - 1) / KT;   // 6
  const int rg = t >> 4;    // 0..15 -> rows rg*2, rg*2+1
  const int cg = t & 15;    // cols cg*4 .. cg*4+3

  float xp[4], wp[8];   // prefetch registers
  #pragma unroll
  for (int j = 0; j < 4; ++j) {
    int e = t + 256 * j; int k = kbeg + (e & 31);
    xp[j] = (k < kend) ? X[(size_t)(r0 + (e >> 5)) * IN_DIM + k] : 0.0f;
  }
  #pragma unroll
  for (int j = 0; j < 8; ++j) {
    int e = t + 256 * j; int k = kbeg + (e >> 6);
    wp[j] = (k < kend) ? w1[(size_t)k * HID + (e & 63)] : 0.0f;
  }

  float acc[2][4] = {};
  for (int tile = 0; tile < ntile; ++tile) {
    #pragma unroll
    for (int j = 0; j < 4; ++j) { int e = t + 256 * j; Xs[e & 31][e >> 5] = xp[j]; }
    #pragma unroll
    for (int j = 0; j < 8; ++j) { int e = t + 256 * j; Ws[e >> 6][e & 63] = wp[j]; }
    __syncthreads();
    if (tile + 1 < ntile) {                // prefetch next tile under the FMAs
      int kn = kbeg + (tile + 1) * KT;
      #pragma unroll
      for (int j = 0; j < 4; ++j) {
        int e = t + 256 * j; int k = kn + (e & 31);
        xp[j] = (k < kend) ? X[(size_t)(r0 + (e >> 5)) * IN_DIM + k] : 0.0f;
      }
      #pragma unroll
      for (int j = 0; j < 8; ++j) {
        int e = t + 256 * j; int k = kn + (e >> 6);
        wp[j] = (k < kend) ? w1[(size_t)k * HID + (e & 63)] : 0.0f;
      }
    }
    #pragma unroll
    for (int kk = 0; kk < KT; ++kk) {
      const float2 xv = *(const float2*)&Xs[kk][rg * 2];
      const float4 wv = *(const float4*)&Ws[kk][cg * 4];
      float xr[2] = {xv.x, xv.y};
      float wc[4] = {wv.x, wv.y, wv.z, wv.w};
      #pragma unroll
      for (int r = 0; r < 2; ++r)
        #pragma unroll
        for (int c = 0; c < 4; ++c) acc[r][c] += xr[r] * wc[c];
    }
    __syncthreads();
  }
  float* Pp = P + (size_t)ks * N_NODES * HID;
  #pragma unroll
  for (int r = 0; r < 2; ++r) {
    int row = r0 + rg * 2 + r;
    *(float4*)&Pp[(size_t)row * HID + cg * 4] =
        make_float4(acc[r][0], acc[r][1], acc[r][2], acc[r][3]);
  }
}

// ---------------------------------------------------------------------------
// Kernel 2b: H = sum over split-K partials (vectorized float4)
// ---------------------------------------------------------------------------
__global__ __launch_bounds__(256) void reduce_h(const float* __restrict__ P,
    float* __restrict__ H) {
  int idx4 = blockIdx.x * 256 + threadIdx.x;
  const float4* P4 = (const float4*)P;
  float4 s = P4[idx4];
  #pragma unroll
  for (int ks = 1; ks < KSPLIT; ++ks) {
    float4 v = P4[(size_t)ks * (N_NODES * HID / 4) + idx4];
    s.x += v.x; s.y += v.y; s.z += v.z; s.w += v.w;
  }
  ((float4*)H)[idx4] = s;
}

// ---------------------------------------------------------------------------
// Kernel 3: F0 = relu(H + b1) @ w2 + b2 ; seed Fcur = F0. Padded stride 8.
// ---------------------------------------------------------------------------
__global__ __launch_bounds__(256) void mlp_out(const float* __restrict__ H,
    const float* __restrict__ b1, const float* __restrict__ w2,
    const float* __restrict__ b2, float* __restrict__ F0, float* __restrict__ Fcur) {
  int t = blockIdx.x * blockDim.x + threadIdx.x;
  if (t >= N_NODES * FPAD) return;
  int row = t >> 3, c = t & 7;
  if (c == 7) { F0[t] = 0.0f; Fcur[t] = 0.0f; return; }
  float acc = b2[c];
  const float* h = H + (size_t)row * HID;
  #pragma unroll
  for (int k = 0; k < HID; ++k) {
    float hv = fmaxf(h[k] + b1[k], 0.0f);
    acc += hv * w2[k * OUT_DIM + c];
  }
  F0[t] = acc;
  Fcur[t] = acc;
}

// ---------------------------------------------------------------------------
// Kernel 4: ALL 10 RUNG steps. Cooperative launch guarantees co-residency;
// grid sync is a hand-rolled sense-reversing barrier (HIP grid.sync() measured
// ~106 us/sync in round 3 — pure spin; this is the fix).
// 256 blocks x 1024 threads = 1 block/CU, 16 waves; wave-per-node.
// ---------------------------------------------------------------------------
__global__ __launch_bounds__(RT, 4) void rung_all(
    float* __restrict__ FA, float* __restrict__ FB,
    const float* __restrict__ F0, float* __restrict__ out,
    const int* __restrict__ nbr, const int* __restrict__ cnt,
    const float* __restrict__ deg, const float* __restrict__ rsd,
    const float* __restrict__ lg0p, const float* __restrict__ rdp,
    int* __restrict__ bar_cnt, int* __restrict__ bar_sense) {
  int wave = threadIdx.x >> 6;
  int lane = threadIdx.x & 63;
  int i = blockIdx.x * (RT / 64) + wave;

  float r_  = 1.0f / (1.0f + expf(-rdp[0]));
  float lam = expf(lg0p[0]) * (1.0f / SCADA);          // lam_0; *= r_ each step

  float rsi = rsd[i];
  float Di  = deg[i];
  int   ci  = cnt[i];
  // hoisted neighbor state: lane covers slots lane and lane+64 (CAP=128)
  int   j0 = -1, j1 = -1;
  float rsj0 = 0.0f, rsj1 = 0.0f;
  if (lane < ci)      { j0 = nbr[(size_t)i * CAP + lane];      rsj0 = rsd[j0]; }
  if (lane + 64 < ci) { j1 = nbr[(size_t)i * CAP + lane + 64]; rsj1 = rsd[j1]; }
  float lf0[OUT_DIM];
  #pragma unroll
  for (int c = 0; c < OUT_DIM; ++c) lf0[c] = LAMBDA * F0[(size_t)i * FPAD + c];

  float* Fin  = FA;
  float* Fout = FB;
  for (int k = 0; k < 10; ++k) {
    if (k) {                             // device barrier: phase value = k
      __syncthreads();
      if (threadIdx.x == 0) {
        __threadfence();                 // release F writes (agent scope)
        int prev = atomicAdd(bar_cnt, 1);
        if (prev == RB - 1) {
          __hip_atomic_store(bar_cnt, 0, __ATOMIC_RELAXED, __HIP_MEMORY_SCOPE_AGENT);
          __hip_atomic_store(bar_sense, k, __ATOMIC_RELEASE, __HIP_MEMORY_SCOPE_AGENT);
        } else {
          while (__hip_atomic_load(bar_sense, __ATOMIC_ACQUIRE,
                                   __HIP_MEMORY_SCOPE_AGENT) < k)
            __builtin_amdgcn_s_sleep(2);
        }
        __threadfence();                 // acquire
      }
      __syncthreads();
    }
    float Fni[FPAD];
    {
      const float4* fp = (const float4*)(Fin + (size_t)i * FPAD);
      float4 a0 = fp[0], a1 = fp[1];
      Fni[0] = a0.x * rsi; Fni[1] = a0.y * rsi; Fni[2] = a0.z * rsi; Fni[3] = a0.w * rsi;
      Fni[4] = a1.x * rsi; Fni[5] = a1.y * rsi; Fni[6] = a1.z * rsi; Fni[7] = a1.w * rsi;
    }
    float s = 0.0f;
    float acc[OUT_DIM] = {0, 0, 0, 0, 0, 0, 0};
    #pragma unroll
    for (int half = 0; half < 2; ++half) {
      int   j   = half ? j1 : j0;
      float rsj = half ? rsj1 : rsj0;
      if (j >= 0) {
        const float4* fp = (const float4*)(Fin + (size_t)j * FPAD);
        float4 b0 = fp[0], b1v = fp[1];
        float fj[FPAD] = {b0.x, b0.y, b0.z, b0.w, b1v.x, b1v.y, b1v.z, b1v.w};
        float d2 = 0.0f;
        #pragma unroll
        for (int c = 0; c < FPAD; ++c) {
          float df = Fni[c] - fj[c] * rsj;
          d2 += df * df;
        }
        float y = sqrtf(d2);
        float w;
        if (y <= lam)              w = 1.0f;
        else if (y <= SCADA * lam) w = (SCADA * lam - y) / ((SCADA - 1.0f) * fmaxf(y, 1e-12f));
        else                       w = 0.0f;
        if (w != w) w = 1.0f;      // NaN guard (matches reference)
        s += w;
        float wr = w * rsi * rsj;  // W_ij * A_tilde_ij
        #pragma unroll
        for (int c = 0; c < OUT_DIM; ++c) acc[c] += wr * fj[c];
      }
    }
    #pragma unroll
    for (int off = 32; off > 0; off >>= 1) {
      s += __shfl_down(s, off);
      #pragma unroll
      for (int c = 0; c < OUT_DIM; ++c) acc[c] += __shfl_down(acc[c], off);
    }
    if (lane == 0) {
      float inv = 1.0f / (s / Di + LAMBDA);
      if (k == 9) {
        #pragma unroll
        for (int c = 0; c < OUT_DIM; ++c)
          out[(size_t)i * OUT_DIM + c] = (acc[c] + lf0[c]) * inv;
      } else {
        float o[OUT_DIM];
        #pragma unroll
        for (int c = 0; c < OUT_DIM; ++c) o[c] = (acc[c] + lf0[c]) * inv;
        float4* op = (float4*)(Fout + (size_t)i * FPAD);
        op[0] = make_float4(o[0], o[1], o[2], o[3]);
        op[1] = make_float4(o[4], o[5], o[6], 0.0f);
      }
    }
    lam *= r_;
    float* tmp = Fin; Fin = Fout; Fout = tmp;
  }
}

// ---------------------------------------------------------------------------
extern "C" void kernel_launch(void* const* d_in, const int* in_sizes, int n_in,
                              void* d_out, int out_size, void* d_ws, size_t ws_size,
                              hipStream_t stream) {
  const float* A   = (const float*)d_in[0];
  const float* X   = (const float*)d_in[1];
  const float* w1  = (const float*)d_in[2];
  const float* b1  = (const float*)d_in[3];
  const float* w2  = (const float*)d_in[4];
  const float* b2  = (const float*)d_in[5];
  const float* lg0 = (const float*)d_in[6];
  const float* rd  = (const float*)d_in[7];
  float* out = (float*)d_out;

  char* w = (char*)d_ws;
  int*   nbr = (int*)w;   w += (size_t)N_NODES * CAP * sizeof(int);
  int*   cnt = (int*)w;   w += (size_t)N_NODES * sizeof(int);
  float* deg = (float*)w; w += (size_t)N_NODES * sizeof(float);
  float* rsd = (float*)w; w += (size_t)N_NODES * sizeof(float);
  float* P   = (float*)w; w += (size_t)KSPLIT * N_NODES * HID * sizeof(float);
  float* H   = (float*)w; w += (size_t)N_NODES * HID * sizeof(float);
  float* F0  = (float*)w; w += (size_t)N_NODES * FPAD * sizeof(float);
  float* FA  = (float*)w; w += (size_t)N_NODES * FPAD * sizeof(float);
  float* FB  = (float*)w; w += (size_t)N_NODES * FPAD * sizeof(float);
  int*   bar = (int*)w;   w += 2 * sizeof(int);        // [cnt, sense]

  hipMemsetAsync(bar, 0, 2 * sizeof(int), stream);     // barrier state must start 0
  build_adj<<<N_NODES, 256, 0, stream>>>(A, nbr, cnt, deg, rsd);
  gemm1<<<dim3(N_NODES / BR, KSPLIT), 256, 0, stream>>>(X, w1, P);
  reduce_h<<<(N_NODES * HID / 4) / 256, 256, 0, stream>>>(P, H);
  mlp_out<<<(N_NODES * FPAD) / 256, 256, 0, stream>>>(H, b1, w2, b2, F0, FA);

  int* bar_cnt   = bar;
  int* bar_sense = bar + 1;
  void* args[] = {&FA, &FB, &F0, &out, &nbr, &cnt, &deg, &rsd,
                  (void*)&lg0, (void*)&rd, &bar_cnt, &bar_sense};
  hipLaunchCooperativeKernel((const void*)rung_all, dim3(RB), dim3(RT),
                             args, 0, stream);
}

// Round 5
// 324.291 us; speedup vs baseline: 3.3898x; 1.1525x over previous
//
#include <hip/hip_runtime.h>
#include <math.h>

#define N_NODES 4096
#define IN_DIM  1433
#define HID     64
#define OUT_DIM 7
#define FPAD    8       // padded feature stride for vectorized gathers
#define CAP     128     // max neighbors per node (avg 32, sigma 5.6; 128 >15 sigma)
#define KSPLIT  8
#define BR      32      // rows per gemm1 block (32 -> 1024 blocks = 4/CU)
#define KT      32      // k-tile
#define RB      256     // rung blocks (1/CU; barrier participants)
#define RT      1024    // rung threads per block (16 waves)

static constexpr float LAMBDA = (float)(1.0 / 0.9 - 1.0);   // 0.11111111
static constexpr float SCADA  = 3.7f;

// ---------------------------------------------------------------------------
// Kernel 1: extract sparse adjacency + degrees from dense binary A (zero diag)
// ---------------------------------------------------------------------------
__global__ __launch_bounds__(256) void build_adj(const float* __restrict__ A,
    int* __restrict__ nbr, int* __restrict__ cnt, float* __restrict__ deg,
    float* __restrict__ rsd) {
  int i = blockIdx.x;
  __shared__ int c;
  if (threadIdx.x == 0) c = 0;
  __syncthreads();
  const float4* row = (const float4*)(A + (size_t)i * N_NODES);
  for (int q = threadIdx.x; q < N_NODES / 4; q += 256) {
    float4 v = row[q];
    int j0 = q * 4;
    if (v.x != 0.0f) { int s = atomicAdd(&c, 1); if (s < CAP) nbr[(size_t)i * CAP + s] = j0; }
    if (v.y != 0.0f) { int s = atomicAdd(&c, 1); if (s < CAP) nbr[(size_t)i * CAP + s] = j0 + 1; }
    if (v.z != 0.0f) { int s = atomicAdd(&c, 1); if (s < CAP) nbr[(size_t)i * CAP + s] = j0 + 2; }
    if (v.w != 0.0f) { int s = atomicAdd(&c, 1); if (s < CAP) nbr[(size_t)i * CAP + s] = j0 + 3; }
  }
  __syncthreads();
  if (threadIdx.x == 0) {
    int cc = c; if (cc > CAP) cc = CAP;
    cnt[i] = cc;
    float d = (float)c + 1.0f;      // + self loop
    deg[i] = d;
    rsd[i] = 1.0f / sqrtf(d);
  }
}

// ---------------------------------------------------------------------------
// Kernel 2: P[ks] = X[:, kchunk] @ w1[kchunk, :]  (split-K partials)
// 1024 blocks (4/CU), register-prefetch pipeline, single LDS buffer.
// ---------------------------------------------------------------------------
__global__ __launch_bounds__(256) void gemm1(const float* __restrict__ X,
    const float* __restrict__ w1, float* __restrict__ P) {
  __shared__ __align__(16) float Xs[KT][BR + 4];
  __shared__ __align__(16) float Ws[KT][HID];
  const int t  = threadIdx.x;
  const int r0 = blockIdx.x * BR;
  const int ks = blockIdx.y;
  const int kbeg = (IN_DIM * ks) / KSPLIT;
  const int kend = (IN_DIM * (ks + 1)) / KSPLIT;
  const int ntile = (kend - kbeg + KT - 1) / KT;   // 6
  const int rg = t >> 4;    // 0..15 -> rows rg*2, rg*2+1
  const int cg = t & 15;    // cols cg*4 .. cg*4+3

  float xp[4], wp[8];   // prefetch registers
  #pragma unroll
  for (int j = 0; j < 4; ++j) {
    int e = t + 256 * j; int k = kbeg + (e & 31);
    xp[j] = (k < kend) ? X[(size_t)(r0 + (e >> 5)) * IN_DIM + k] : 0.0f;
  }
  #pragma unroll
  for (int j = 0; j < 8; ++j) {
    int e = t + 256 * j; int k = kbeg + (e >> 6);
    wp[j] = (k < kend) ? w1[(size_t)k * HID + (e & 63)] : 0.0f;
  }

  float acc[2][4] = {};
  for (int tile = 0; tile < ntile; ++tile) {
    #pragma unroll
    for (int j = 0; j < 4; ++j) { int e = t + 256 * j; Xs[e & 31][e >> 5] = xp[j]; }
    #pragma unroll
    for (int j = 0; j < 8; ++j) { int e = t + 256 * j; Ws[e >> 6][e & 63] = wp[j]; }
    __syncthreads();
    if (tile + 1 < ntile) {                // prefetch next tile under the FMAs
      int kn = kbeg + (tile + 1) * KT;
      #pragma unroll
      for (int j = 0; j < 4; ++j) {
        int e = t + 256 * j; int k = kn + (e & 31);
        xp[j] = (k < kend) ? X[(size_t)(r0 + (e >> 5)) * IN_DIM + k] : 0.0f;
      }
      #pragma unroll
      for (int j = 0; j < 8; ++j) {
        int e = t + 256 * j; int k = kn + (e >> 6);
        wp[j] = (k < kend) ? w1[(size_t)k * HID + (e & 63)] : 0.0f;
      }
    }
    #pragma unroll
    for (int kk = 0; kk < KT; ++kk) {
      const float2 xv = *(const float2*)&Xs[kk][rg * 2];
      const float4 wv = *(const float4*)&Ws[kk][cg * 4];
      float xr[2] = {xv.x, xv.y};
      float wc[4] = {wv.x, wv.y, wv.z, wv.w};
      #pragma unroll
      for (int r = 0; r < 2; ++r)
        #pragma unroll
        for (int c = 0; c < 4; ++c) acc[r][c] += xr[r] * wc[c];
    }
    __syncthreads();
  }
  float* Pp = P + (size_t)ks * N_NODES * HID;
  #pragma unroll
  for (int r = 0; r < 2; ++r) {
    int row = r0 + rg * 2 + r;
    *(float4*)&Pp[(size_t)row * HID + cg * 4] =
        make_float4(acc[r][0], acc[r][1], acc[r][2], acc[r][3]);
  }
}

// ---------------------------------------------------------------------------
// Kernel 2b: H = sum over split-K partials (vectorized float4)
// ---------------------------------------------------------------------------
__global__ __launch_bounds__(256) void reduce_h(const float* __restrict__ P,
    float* __restrict__ H) {
  int idx4 = blockIdx.x * 256 + threadIdx.x;
  const float4* P4 = (const float4*)P;
  float4 s = P4[idx4];
  #pragma unroll
  for (int ks = 1; ks < KSPLIT; ++ks) {
    float4 v = P4[(size_t)ks * (N_NODES * HID / 4) + idx4];
    s.x += v.x; s.y += v.y; s.z += v.z; s.w += v.w;
  }
  ((float4*)H)[idx4] = s;
}

// ---------------------------------------------------------------------------
// Kernel 3: F0 = relu(H + b1) @ w2 + b2 ; seed Fcur = F0. Padded stride 8.
// ---------------------------------------------------------------------------
__global__ __launch_bounds__(256) void mlp_out(const float* __restrict__ H,
    const float* __restrict__ b1, const float* __restrict__ w2,
    const float* __restrict__ b2, float* __restrict__ F0, float* __restrict__ Fcur) {
  int t = blockIdx.x * blockDim.x + threadIdx.x;
  if (t >= N_NODES * FPAD) return;
  int row = t >> 3, c = t & 7;
  if (c == 7) { F0[t] = 0.0f; Fcur[t] = 0.0f; return; }
  float acc = b2[c];
  const float* h = H + (size_t)row * HID;
  #pragma unroll
  for (int k = 0; k < HID; ++k) {
    float hv = fmaxf(h[k] + b1[k], 0.0f);
    acc += hv * w2[k * OUT_DIM + c];
  }
  F0[t] = acc;
  Fcur[t] = acc;
}

// ---------------------------------------------------------------------------
// Kernel 4: ALL 10 RUNG steps, one cooperative kernel, wave-per-node.
// Barrier v2 (round-4 post-mortem): the round-4 spin used ACQUIRE per poll ->
// L2 flash-invalidate every ~128 cycles (20 us/step). Now: RELAXED spin +
// ONE release fence (wbl2) before arrive + ONE acquire fence (inv) after exit.
// Own row F_i carried in registers (butterfly reduce -> all lanes have it);
// only neighbor gathers touch memory inside the step loop.
// ---------------------------------------------------------------------------
__global__ __launch_bounds__(RT, 4) void rung_all(
    float* __restrict__ FA, float* __restrict__ FB,
    const float* __restrict__ F0, float* __restrict__ out,
    const int* __restrict__ nbr, const int* __restrict__ cnt,
    const float* __restrict__ deg, const float* __restrict__ rsd,
    const float* __restrict__ lg0p, const float* __restrict__ rdp,
    int* __restrict__ bar_cnt, int* __restrict__ bar_sense) {
  int wave = threadIdx.x >> 6;
  int lane = threadIdx.x & 63;
  int i = blockIdx.x * (RT / 64) + wave;

  float r_  = 1.0f / (1.0f + expf(-rdp[0]));
  float lam = expf(lg0p[0]) * (1.0f / SCADA);          // lam_0; *= r_ each step

  float rsi = rsd[i];
  float Di  = deg[i];
  int   ci  = cnt[i];
  // hoisted neighbor state: lane covers slots lane and lane+64 (CAP=128)
  int   j0 = -1, j1 = -1;
  float rsj0 = 0.0f, rsj1 = 0.0f;
  if (lane < ci)      { j0 = nbr[(size_t)i * CAP + lane];      rsj0 = rsd[j0]; }
  if (lane + 64 < ci) { j1 = nbr[(size_t)i * CAP + lane + 64]; rsj1 = rsd[j1]; }
  float lf0[OUT_DIM];
  #pragma unroll
  for (int c = 0; c < OUT_DIM; ++c) lf0[c] = LAMBDA * F0[(size_t)i * FPAD + c];

  // own row carried in registers (all lanes)
  float myF[FPAD];
  {
    const float4* fp = (const float4*)(FA + (size_t)i * FPAD);
    float4 a0 = fp[0], a1 = fp[1];
    myF[0] = a0.x; myF[1] = a0.y; myF[2] = a0.z; myF[3] = a0.w;
    myF[4] = a1.x; myF[5] = a1.y; myF[6] = a1.z; myF[7] = a1.w;
  }

  float* Fin  = FA;
  float* Fout = FB;
  for (int k = 0; k < 10; ++k) {
    if (k) {
      __syncthreads();                   // all block stores now in L2 (vmcnt drain)
      if (threadIdx.x == 0) {
        __builtin_amdgcn_fence(__ATOMIC_RELEASE, "agent");   // wbl2: publish to L3
        int prev = __hip_atomic_fetch_add(bar_cnt, 1, __ATOMIC_RELAXED,
                                          __HIP_MEMORY_SCOPE_AGENT);
        if (prev == RB - 1) {
          __hip_atomic_store(bar_cnt, 0, __ATOMIC_RELAXED, __HIP_MEMORY_SCOPE_AGENT);
          // RELEASE orders the cnt reset before the sense release
          __hip_atomic_store(bar_sense, k, __ATOMIC_RELEASE, __HIP_MEMORY_SCOPE_AGENT);
        } else {
          while (__hip_atomic_load(bar_sense, __ATOMIC_RELAXED,
                                   __HIP_MEMORY_SCOPE_AGENT) < k)
            __builtin_amdgcn_s_sleep(8);                     // RELAXED: no inv per poll
        }
        __builtin_amdgcn_fence(__ATOMIC_ACQUIRE, "agent");   // single inv
      }
      __syncthreads();
    }
    float Fni[FPAD];
    #pragma unroll
    for (int c = 0; c < FPAD; ++c) Fni[c] = myF[c] * rsi;

    float s = 0.0f;
    float acc[OUT_DIM] = {0, 0, 0, 0, 0, 0, 0};
    #pragma unroll
    for (int half = 0; half < 2; ++half) {
      int   j   = half ? j1 : j0;
      float rsj = half ? rsj1 : rsj0;
      if (j >= 0) {
        const float4* fp = (const float4*)(Fin + (size_t)j * FPAD);
        float4 b0 = fp[0], b1v = fp[1];
        float fj[FPAD] = {b0.x, b0.y, b0.z, b0.w, b1v.x, b1v.y, b1v.z, b1v.w};
        float d2 = 0.0f;
        #pragma unroll
        for (int c = 0; c < FPAD; ++c) {
          float df = Fni[c] - fj[c] * rsj;
          d2 += df * df;
        }
        float y = sqrtf(d2);
        float w;
        if (y <= lam)              w = 1.0f;
        else if (y <= SCADA * lam) w = (SCADA * lam - y) / ((SCADA - 1.0f) * fmaxf(y, 1e-12f));
        else                       w = 0.0f;
        if (w != w) w = 1.0f;      // NaN guard (matches reference)
        s += w;
        float wr = w * rsi * rsj;  // W_ij * A_tilde_ij
        #pragma unroll
        for (int c = 0; c < OUT_DIM; ++c) acc[c] += wr * fj[c];
      }
    }
    // butterfly reduction: ALL lanes end with the totals
    #pragma unroll
    for (int off = 1; off < 64; off <<= 1) {
      s += __shfl_xor(s, off);
      #pragma unroll
      for (int c = 0; c < OUT_DIM; ++c) acc[c] += __shfl_xor(acc[c], off);
    }
    float inv = 1.0f / (s / Di + LAMBDA);
    if (k == 9) {
      if (lane < OUT_DIM)
        out[(size_t)i * OUT_DIM + lane] = (acc[lane] + lf0[lane]) * inv;
    } else {
      #pragma unroll
      for (int c = 0; c < OUT_DIM; ++c) myF[c] = (acc[c] + lf0[c]) * inv;
      myF[7] = 0.0f;
      if (lane == 0) {
        float4* op = (float4*)(Fout + (size_t)i * FPAD);
        op[0] = make_float4(myF[0], myF[1], myF[2], myF[3]);
        op[1] = make_float4(myF[4], myF[5], myF[6], 0.0f);
      }
    }
    lam *= r_;
    float* tmp = Fin; Fin = Fout; Fout = tmp;
  }
}

// ---------------------------------------------------------------------------
extern "C" void kernel_launch(void* const* d_in, const int* in_sizes, int n_in,
                              void* d_out, int out_size, void* d_ws, size_t ws_size,
                              hipStream_t stream) {
  const float* A   = (const float*)d_in[0];
  const float* X   = (const float*)d_in[1];
  const float* w1  = (const float*)d_in[2];
  const float* b1  = (const float*)d_in[3];
  const float* w2  = (const float*)d_in[4];
  const float* b2  = (const float*)d_in[5];
  const float* lg0 = (const float*)d_in[6];
  const float* rd  = (const float*)d_in[7];
  float* out = (float*)d_out;

  char* w = (char*)d_ws;
  int*   nbr = (int*)w;   w += (size_t)N_NODES * CAP * sizeof(int);
  int*   cnt = (int*)w;   w += (size_t)N_NODES * sizeof(int);
  float* deg = (float*)w; w += (size_t)N_NODES * sizeof(float);
  float* rsd = (float*)w; w += (size_t)N_NODES * sizeof(float);
  float* P   = (float*)w; w += (size_t)KSPLIT * N_NODES * HID * sizeof(float);
  float* H   = (float*)w; w += (size_t)N_NODES * HID * sizeof(float);
  float* F0  = (float*)w; w += (size_t)N_NODES * FPAD * sizeof(float);
  float* FA  = (float*)w; w += (size_t)N_NODES * FPAD * sizeof(float);
  float* FB  = (float*)w; w += (size_t)N_NODES * FPAD * sizeof(float);
  int*   bar = (int*)w;   w += 2 * sizeof(int);        // [cnt, sense]

  hipMemsetAsync(bar, 0, 2 * sizeof(int), stream);     // barrier state must start 0
  build_adj<<<N_NODES, 256, 0, stream>>>(A, nbr, cnt, deg, rsd);
  gemm1<<<dim3(N_NODES / BR, KSPLIT), 256, 0, stream>>>(X, w1, P);
  reduce_h<<<(N_NODES * HID / 4) / 256, 256, 0, stream>>>(P, H);
  mlp_out<<<(N_NODES * FPAD) / 256, 256, 0, stream>>>(H, b1, w2, b2, F0, FA);

  int* bar_cnt   = bar;
  int* bar_sense = bar + 1;
  void* args[] = {&FA, &FB, &F0, &out, &nbr, &cnt, &deg, &rsd,
                  (void*)&lg0, (void*)&rd, &bar_cnt, &bar_sense};
  hipLaunchCooperativeKernel((const void*)rung_all, dim3(RB), dim3(RT),
                             args, 0, stream);
}

// Round 6
// 308.892 us; speedup vs baseline: 3.5588x; 1.0499x over previous
//
#include <hip/hip_runtime.h>
#include <math.h>

#define N_NODES 4096
#define IN_DIM  1433
#define HID     64
#define OUT_DIM 7
#define FPAD    8       // padded feature stride for vectorized gathers
#define CAP     128     // max neighbors per node (avg 32, sigma 5.6; 128 >15 sigma)
#define KSPLIT  8
#define BR      32      // rows per gemm1 block (32 -> 1024 blocks = 4/CU)
#define KT      32      // k-tile
#define RB      256     // rung blocks (1/CU; barrier participants)
#define RT      1024    // rung threads per block (16 waves)

static constexpr float LAMBDA = (float)(1.0 / 0.9 - 1.0);   // 0.11111111
static constexpr float SCADA  = 3.7f;

typedef unsigned long long u64;

// Coherence-point (L1/L2-bypass) 8-byte load/store: compile to
// global_load/store_dwordx2 sc0 sc1 -> served at the device coherence point.
// No stale caching, no dirty L2 => the inter-step barrier needs NO fences
// (round-5 post-mortem: per-block agent fences = full L2 tag walks = 14 us/step).
__device__ __forceinline__ float2 ldcoh8(const float* p) {
  u64 v = __hip_atomic_load((const u64*)p, __ATOMIC_RELAXED,
                            __HIP_MEMORY_SCOPE_AGENT);
  float2 r;
  r.x = __uint_as_float((unsigned)(v & 0xffffffffull));
  r.y = __uint_as_float((unsigned)(v >> 32));
  return r;
}
__device__ __forceinline__ void stcoh8(float* p, float a, float b) {
  u64 v = ((u64)__float_as_uint(b) << 32) | (u64)__float_as_uint(a);
  __hip_atomic_store((u64*)p, v, __ATOMIC_RELAXED, __HIP_MEMORY_SCOPE_AGENT);
}

// ---------------------------------------------------------------------------
// Kernel 1: extract sparse adjacency + degrees from dense binary A (zero diag)
// ---------------------------------------------------------------------------
__global__ __launch_bounds__(256) void build_adj(const float* __restrict__ A,
    int* __restrict__ nbr, int* __restrict__ cnt, float* __restrict__ deg,
    float* __restrict__ rsd) {
  int i = blockIdx.x;
  __shared__ int c;
  if (threadIdx.x == 0) c = 0;
  __syncthreads();
  const float4* row = (const float4*)(A + (size_t)i * N_NODES);
  for (int q = threadIdx.x; q < N_NODES / 4; q += 256) {
    float4 v = row[q];
    int j0 = q * 4;
    if (v.x != 0.0f) { int s = atomicAdd(&c, 1); if (s < CAP) nbr[(size_t)i * CAP + s] = j0; }
    if (v.y != 0.0f) { int s = atomicAdd(&c, 1); if (s < CAP) nbr[(size_t)i * CAP + s] = j0 + 1; }
    if (v.z != 0.0f) { int s = atomicAdd(&c, 1); if (s < CAP) nbr[(size_t)i * CAP + s] = j0 + 2; }
    if (v.w != 0.0f) { int s = atomicAdd(&c, 1); if (s < CAP) nbr[(size_t)i * CAP + s] = j0 + 3; }
  }
  __syncthreads();
  if (threadIdx.x == 0) {
    int cc = c; if (cc > CAP) cc = CAP;
    cnt[i] = cc;
    float d = (float)c + 1.0f;      // + self loop
    deg[i] = d;
    rsd[i] = 1.0f / sqrtf(d);
  }
}

// ---------------------------------------------------------------------------
// Kernel 2: P[ks] = X[:, kchunk] @ w1[kchunk, :]  (split-K partials)
// 1024 blocks (4/CU), register-prefetch pipeline, single LDS buffer.
// ---------------------------------------------------------------------------
__global__ __launch_bounds__(256) void gemm1(const float* __restrict__ X,
    const float* __restrict__ w1, float* __restrict__ P) {
  __shared__ __align__(16) float Xs[KT][BR + 4];
  __shared__ __align__(16) float Ws[KT][HID];
  const int t  = threadIdx.x;
  const int r0 = blockIdx.x * BR;
  const int ks = blockIdx.y;
  const int kbeg = (IN_DIM * ks) / KSPLIT;
  const int kend = (IN_DIM * (ks + 1)) / KSPLIT;
  const int ntile = (kend - kbeg + KT - 1) / KT;   // 6
  const int rg = t >> 4;    // 0..15 -> rows rg*2, rg*2+1
  const int cg = t & 15;    // cols cg*4 .. cg*4+3

  float xp[4], wp[8];   // prefetch registers
  #pragma unroll
  for (int j = 0; j < 4; ++j) {
    int e = t + 256 * j; int k = kbeg + (e & 31);
    xp[j] = (k < kend) ? X[(size_t)(r0 + (e >> 5)) * IN_DIM + k] : 0.0f;
  }
  #pragma unroll
  for (int j = 0; j < 8; ++j) {
    int e = t + 256 * j; int k = kbeg + (e >> 6);
    wp[j] = (k < kend) ? w1[(size_t)k * HID + (e & 63)] : 0.0f;
  }

  float acc[2][4] = {};
  for (int tile = 0; tile < ntile; ++tile) {
    #pragma unroll
    for (int j = 0; j < 4; ++j) { int e = t + 256 * j; Xs[e & 31][e >> 5] = xp[j]; }
    #pragma unroll
    for (int j = 0; j < 8; ++j) { int e = t + 256 * j; Ws[e >> 6][e & 63] = wp[j]; }
    __syncthreads();
    if (tile + 1 < ntile) {                // prefetch next tile under the FMAs
      int kn = kbeg + (tile + 1) * KT;
      #pragma unroll
      for (int j = 0; j < 4; ++j) {
        int e = t + 256 * j; int k = kn + (e & 31);
        xp[j] = (k < kend) ? X[(size_t)(r0 + (e >> 5)) * IN_DIM + k] : 0.0f;
      }
      #pragma unroll
      for (int j = 0; j < 8; ++j) {
        int e = t + 256 * j; int k = kn + (e >> 6);
        wp[j] = (k < kend) ? w1[(size_t)k * HID + (e & 63)] : 0.0f;
      }
    }
    #pragma unroll
    for (int kk = 0; kk < KT; ++kk) {
      const float2 xv = *(const float2*)&Xs[kk][rg * 2];
      const float4 wv = *(const float4*)&Ws[kk][cg * 4];
      float xr[2] = {xv.x, xv.y};
      float wc[4] = {wv.x, wv.y, wv.z, wv.w};
      #pragma unroll
      for (int r = 0; r < 2; ++r)
        #pragma unroll
        for (int c = 0; c < 4; ++c) acc[r][c] += xr[r] * wc[c];
    }
    __syncthreads();
  }
  float* Pp = P + (size_t)ks * N_NODES * HID;
  #pragma unroll
  for (int r = 0; r < 2; ++r) {
    int row = r0 + rg * 2 + r;
    *(float4*)&Pp[(size_t)row * HID + cg * 4] =
        make_float4(acc[r][0], acc[r][1], acc[r][2], acc[r][3]);
  }
}

// ---------------------------------------------------------------------------
// Kernel 2b: H = sum over split-K partials (vectorized float4)
// ---------------------------------------------------------------------------
__global__ __launch_bounds__(256) void reduce_h(const float* __restrict__ P,
    float* __restrict__ H) {
  int idx4 = blockIdx.x * 256 + threadIdx.x;
  const float4* P4 = (const float4*)P;
  float4 s = P4[idx4];
  #pragma unroll
  for (int ks = 1; ks < KSPLIT; ++ks) {
    float4 v = P4[(size_t)ks * (N_NODES * HID / 4) + idx4];
    s.x += v.x; s.y += v.y; s.z += v.z; s.w += v.w;
  }
  ((float4*)H)[idx4] = s;
}

// ---------------------------------------------------------------------------
// Kernel 3: F0 = relu(H + b1) @ w2 + b2 ; seed Fcur = F0. Padded stride 8.
// ---------------------------------------------------------------------------
__global__ __launch_bounds__(256) void mlp_out(const float* __restrict__ H,
    const float* __restrict__ b1, const float* __restrict__ w2,
    const float* __restrict__ b2, float* __restrict__ F0, float* __restrict__ Fcur) {
  int t = blockIdx.x * blockDim.x + threadIdx.x;
  if (t >= N_NODES * FPAD) return;
  int row = t >> 3, c = t & 7;
  if (c == 7) { F0[t] = 0.0f; Fcur[t] = 0.0f; return; }
  float acc = b2[c];
  const float* h = H + (size_t)row * HID;
  #pragma unroll
  for (int k = 0; k < HID; ++k) {
    float hv = fmaxf(h[k] + b1[k], 0.0f);
    acc += hv * w2[k * OUT_DIM + c];
  }
  F0[t] = acc;
  Fcur[t] = acc;
}

// ---------------------------------------------------------------------------
// Kernel 4: ALL 10 RUNG steps, one cooperative kernel, wave-per-node.
// Barrier v3: ZERO fences. All inter-step F traffic uses coherence-point
// loads/stores (ldcoh8/stcoh8 -> sc0 sc1, bypass L1+L2), so there is no
// cached state to flush/invalidate. Barrier = monotone arrival counter
// (spin until cnt >= k*RB): no reset, no sense word, no release ordering.
// __syncthreads() drains vmcnt before s_barrier -> block's data stores are
// at the coherence point before thread 0's arrival RMW.
// ---------------------------------------------------------------------------
__global__ __launch_bounds__(RT, 4) void rung_all(
    float* __restrict__ FA, float* __restrict__ FB,
    const float* __restrict__ F0, float* __restrict__ out,
    const int* __restrict__ nbr, const int* __restrict__ cnt,
    const float* __restrict__ deg, const float* __restrict__ rsd,
    const float* __restrict__ lg0p, const float* __restrict__ rdp,
    int* __restrict__ bar_cnt) {
  int wave = threadIdx.x >> 6;
  int lane = threadIdx.x & 63;
  int i = blockIdx.x * (RT / 64) + wave;

  float r_  = 1.0f / (1.0f + expf(-rdp[0]));
  float lam = expf(lg0p[0]) * (1.0f / SCADA);          // lam_0; *= r_ each step

  float rsi = rsd[i];
  float Di  = deg[i];
  int   ci  = cnt[i];
  // hoisted neighbor state: lane covers slots lane and lane+64 (CAP=128)
  int   j0 = -1, j1 = -1;
  float rsj0 = 0.0f, rsj1 = 0.0f;
  if (lane < ci)      { j0 = nbr[(size_t)i * CAP + lane];      rsj0 = rsd[j0]; }
  if (lane + 64 < ci) { j1 = nbr[(size_t)i * CAP + lane + 64]; rsj1 = rsd[j1]; }
  float lf0[OUT_DIM];
  #pragma unroll
  for (int c = 0; c < OUT_DIM; ++c) lf0[c] = LAMBDA * F0[(size_t)i * FPAD + c];

  // own row carried in registers (all lanes, via butterfly reduction)
  float myF[FPAD];
  {
    const float4* fp = (const float4*)(FA + (size_t)i * FPAD);
    float4 a0 = fp[0], a1 = fp[1];
    myF[0] = a0.x; myF[1] = a0.y; myF[2] = a0.z; myF[3] = a0.w;
    myF[4] = a1.x; myF[5] = a1.y; myF[6] = a1.z; myF[7] = a1.w;
  }

  float* Fin  = FA;
  float* Fout = FB;
  for (int k = 0; k < 10; ++k) {
    if (k) {
      __syncthreads();                  // drains vmcnt: stores at coherence point
      if (threadIdx.x == 0) {
        __hip_atomic_fetch_add(bar_cnt, 1, __ATOMIC_RELAXED,
                               __HIP_MEMORY_SCOPE_AGENT);
        int target = k * RB;            // monotone: no reset, no reuse race
        while (__hip_atomic_load(bar_cnt, __ATOMIC_RELAXED,
                                 __HIP_MEMORY_SCOPE_AGENT) < target)
          __builtin_amdgcn_s_sleep(1);
      }
      __syncthreads();
    }
    float Fni[FPAD];
    #pragma unroll
    for (int c = 0; c < FPAD; ++c) Fni[c] = myF[c] * rsi;

    float s = 0.0f;
    float acc[OUT_DIM] = {0, 0, 0, 0, 0, 0, 0};
    #pragma unroll
    for (int half = 0; half < 2; ++half) {
      int   j   = half ? j1 : j0;
      float rsj = half ? rsj1 : rsj0;
      if (j >= 0) {
        const float* base = Fin + (size_t)j * FPAD;
        float2 g0 = ldcoh8(base);
        float2 g1 = ldcoh8(base + 2);
        float2 g2 = ldcoh8(base + 4);
        float2 g3 = ldcoh8(base + 6);
        float fj[FPAD] = {g0.x, g0.y, g1.x, g1.y, g2.x, g2.y, g3.x, g3.y};
        float d2 = 0.0f;
        #pragma unroll
        for (int c = 0; c < FPAD; ++c) {
          float df = Fni[c] - fj[c] * rsj;
          d2 += df * df;
        }
        float y = sqrtf(d2);
        float w;
        if (y <= lam)              w = 1.0f;
        else if (y <= SCADA * lam) w = (SCADA * lam - y) / ((SCADA - 1.0f) * fmaxf(y, 1e-12f));
        else                       w = 0.0f;
        if (w != w) w = 1.0f;      // NaN guard (matches reference)
        s += w;
        float wr = w * rsi * rsj;  // W_ij * A_tilde_ij
        #pragma unroll
        for (int c = 0; c < OUT_DIM; ++c) acc[c] += wr * fj[c];
      }
    }
    // butterfly reduction: ALL lanes end with the totals
    #pragma unroll
    for (int off = 1; off < 64; off <<= 1) {
      s += __shfl_xor(s, off);
      #pragma unroll
      for (int c = 0; c < OUT_DIM; ++c) acc[c] += __shfl_xor(acc[c], off);
    }
    float inv = 1.0f / (s / Di + LAMBDA);
    if (k == 9) {
      if (lane < OUT_DIM)
        out[(size_t)i * OUT_DIM + lane] = (acc[lane] + lf0[lane]) * inv;
    } else {
      #pragma unroll
      for (int c = 0; c < OUT_DIM; ++c) myF[c] = (acc[c] + lf0[c]) * inv;
      myF[7] = 0.0f;
      if (lane == 0) {
        float* op = Fout + (size_t)i * FPAD;
        stcoh8(op,     myF[0], myF[1]);
        stcoh8(op + 2, myF[2], myF[3]);
        stcoh8(op + 4, myF[4], myF[5]);
        stcoh8(op + 6, myF[6], 0.0f);
      }
    }
    lam *= r_;
    float* tmp = Fin; Fin = Fout; Fout = tmp;
  }
}

// ---------------------------------------------------------------------------
extern "C" void kernel_launch(void* const* d_in, const int* in_sizes, int n_in,
                              void* d_out, int out_size, void* d_ws, size_t ws_size,
                              hipStream_t stream) {
  const float* A   = (const float*)d_in[0];
  const float* X   = (const float*)d_in[1];
  const float* w1  = (const float*)d_in[2];
  const float* b1  = (const float*)d_in[3];
  const float* w2  = (const float*)d_in[4];
  const float* b2  = (const float*)d_in[5];
  const float* lg0 = (const float*)d_in[6];
  const float* rd  = (const float*)d_in[7];
  float* out = (float*)d_out;

  char* w = (char*)d_ws;
  int*   nbr = (int*)w;   w += (size_t)N_NODES * CAP * sizeof(int);
  int*   cnt = (int*)w;   w += (size_t)N_NODES * sizeof(int);
  float* deg = (float*)w; w += (size_t)N_NODES * sizeof(float);
  float* rsd = (float*)w; w += (size_t)N_NODES * sizeof(float);
  float* P   = (float*)w; w += (size_t)KSPLIT * N_NODES * HID * sizeof(float);
  float* H   = (float*)w; w += (size_t)N_NODES * HID * sizeof(float);
  float* F0  = (float*)w; w += (size_t)N_NODES * FPAD * sizeof(float);
  float* FA  = (float*)w; w += (size_t)N_NODES * FPAD * sizeof(float);
  float* FB  = (float*)w; w += (size_t)N_NODES * FPAD * sizeof(float);
  int*   bar = (int*)w;   w += sizeof(int);            // monotone arrival counter

  hipMemsetAsync(bar, 0, sizeof(int), stream);         // must start at 0
  build_adj<<<N_NODES, 256, 0, stream>>>(A, nbr, cnt, deg, rsd);
  gemm1<<<dim3(N_NODES / BR, KSPLIT), 256, 0, stream>>>(X, w1, P);
  reduce_h<<<(N_NODES * HID / 4) / 256, 256, 0, stream>>>(P, H);
  mlp_out<<<(N_NODES * FPAD) / 256, 256, 0, stream>>>(H, b1, w2, b2, F0, FA);

  void* args[] = {&FA, &FB, &F0, &out, &nbr, &cnt, &deg, &rsd,
                  (void*)&lg0, (void*)&rd, &bar};
  hipLaunchCooperativeKernel((const void*)rung_all, dim3(RB), dim3(RT),
                             args, 0, stream);
}

// Round 7
// 232.162 us; speedup vs baseline: 4.7350x; 1.3305x over previous
//
#include <hip/hip_runtime.h>
#include <math.h>

#define N_NODES 4096
#define IN_DIM  1433
#define HID     64
#define OUT_DIM 7
#define FPAD    8       // padded feature stride for vectorized gathers
#define CAP     128     // max neighbors per node (avg 32, sigma 5.6; 128 >15 sigma)
#define KSPLIT  8
#define BR      32      // rows per gemm1 block (32 -> 1024 blocks = 4/CU)
#define KT      32      // k-tile
#define RB      256     // rung blocks (1/CU; barrier participants)
#define RT      1024    // rung threads per block (16 waves)
#define NSTEP   10

static constexpr float LAMBDA = (float)(1.0 / 0.9 - 1.0);   // 0.11111111
static constexpr float SCADA  = 3.7f;

typedef unsigned long long u64;

// Relaxed agent-scope primitives (compile to sc0 sc1 bypass ops; no fences).
__device__ __forceinline__ int ldflag(const int* p) {
  return __hip_atomic_load(p, __ATOMIC_RELAXED, __HIP_MEMORY_SCOPE_AGENT);
}
__device__ __forceinline__ void stflag(int* p, int v) {
  __hip_atomic_store(p, v, __ATOMIC_RELAXED, __HIP_MEMORY_SCOPE_AGENT);
}
// Write-through 8B store: publishes F rows to the coherence point so that
// other XCDs' cached loads (of never-before-cached addresses) see fresh data.
__device__ __forceinline__ void stcoh8(float* p, float a, float b) {
  u64 v = ((u64)__float_as_uint(b) << 32) | (u64)__float_as_uint(a);
  __hip_atomic_store((u64*)p, v, __ATOMIC_RELAXED, __HIP_MEMORY_SCOPE_AGENT);
}

// ---------------------------------------------------------------------------
// Kernel 1: extract sparse adjacency + degrees from dense binary A (zero diag)
// ---------------------------------------------------------------------------
__global__ __launch_bounds__(256) void build_adj(const float* __restrict__ A,
    int* __restrict__ nbr, int* __restrict__ cnt, float* __restrict__ deg,
    float* __restrict__ rsd) {
  int i = blockIdx.x;
  __shared__ int c;
  if (threadIdx.x == 0) c = 0;
  __syncthreads();
  const float4* row = (const float4*)(A + (size_t)i * N_NODES);
  for (int q = threadIdx.x; q < N_NODES / 4; q += 256) {
    float4 v = row[q];
    int j0 = q * 4;
    if (v.x != 0.0f) { int s = atomicAdd(&c, 1); if (s < CAP) nbr[(size_t)i * CAP + s] = j0; }
    if (v.y != 0.0f) { int s = atomicAdd(&c, 1); if (s < CAP) nbr[(size_t)i * CAP + s] = j0 + 1; }
    if (v.z != 0.0f) { int s = atomicAdd(&c, 1); if (s < CAP) nbr[(size_t)i * CAP + s] = j0 + 2; }
    if (v.w != 0.0f) { int s = atomicAdd(&c, 1); if (s < CAP) nbr[(size_t)i * CAP + s] = j0 + 3; }
  }
  __syncthreads();
  if (threadIdx.x == 0) {
    int cc = c; if (cc > CAP) cc = CAP;
    cnt[i] = cc;
    float d = (float)c + 1.0f;      // + self loop
    deg[i] = d;
    rsd[i] = 1.0f / sqrtf(d);
  }
}

// ---------------------------------------------------------------------------
// Kernel 2: P[ks] = X[:, kchunk] @ w1[kchunk, :]  (split-K partials)
// ---------------------------------------------------------------------------
__global__ __launch_bounds__(256) void gemm1(const float* __restrict__ X,
    const float* __restrict__ w1, float* __restrict__ P) {
  __shared__ __align__(16) float Xs[KT][BR + 4];
  __shared__ __align__(16) float Ws[KT][HID];
  const int t  = threadIdx.x;
  const int r0 = blockIdx.x * BR;
  const int ks = blockIdx.y;
  const int kbeg = (IN_DIM * ks) / KSPLIT;
  const int kend = (IN_DIM * (ks + 1)) / KSPLIT;
  const int ntile = (kend - kbeg + KT - 1) / KT;   // 6
  const int rg = t >> 4;
  const int cg = t & 15;

  float xp[4], wp[8];
  #pragma unroll
  for (int j = 0; j < 4; ++j) {
    int e = t + 256 * j; int k = kbeg + (e & 31);
    xp[j] = (k < kend) ? X[(size_t)(r0 + (e >> 5)) * IN_DIM + k] : 0.0f;
  }
  #pragma unroll
  for (int j = 0; j < 8; ++j) {
    int e = t + 256 * j; int k = kbeg + (e >> 6);
    wp[j] = (k < kend) ? w1[(size_t)k * HID + (e & 63)] : 0.0f;
  }

  float acc[2][4] = {};
  for (int tile = 0; tile < ntile; ++tile) {
    #pragma unroll
    for (int j = 0; j < 4; ++j) { int e = t + 256 * j; Xs[e & 31][e >> 5] = xp[j]; }
    #pragma unroll
    for (int j = 0; j < 8; ++j) { int e = t + 256 * j; Ws[e >> 6][e & 63] = wp[j]; }
    __syncthreads();
    if (tile + 1 < ntile) {
      int kn = kbeg + (tile + 1) * KT;
      #pragma unroll
      for (int j = 0; j < 4; ++j) {
        int e = t + 256 * j; int k = kn + (e & 31);
        xp[j] = (k < kend) ? X[(size_t)(r0 + (e >> 5)) * IN_DIM + k] : 0.0f;
      }
      #pragma unroll
      for (int j = 0; j < 8; ++j) {
        int e = t + 256 * j; int k = kn + (e >> 6);
        wp[j] = (k < kend) ? w1[(size_t)k * HID + (e & 63)] : 0.0f;
      }
    }
    #pragma unroll
    for (int kk = 0; kk < KT; ++kk) {
      const float2 xv = *(const float2*)&Xs[kk][rg * 2];
      const float4 wv = *(const float4*)&Ws[kk][cg * 4];
      float xr[2] = {xv.x, xv.y};
      float wc[4] = {wv.x, wv.y, wv.z, wv.w};
      #pragma unroll
      for (int r = 0; r < 2; ++r)
        #pragma unroll
        for (int c = 0; c < 4; ++c) acc[r][c] += xr[r] * wc[c];
    }
    __syncthreads();
  }
  float* Pp = P + (size_t)ks * N_NODES * HID;
  #pragma unroll
  for (int r = 0; r < 2; ++r) {
    int row = r0 + rg * 2 + r;
    *(float4*)&Pp[(size_t)row * HID + cg * 4] =
        make_float4(acc[r][0], acc[r][1], acc[r][2], acc[r][3]);
  }
}

// ---------------------------------------------------------------------------
// Kernel 2b: H = sum over split-K partials (vectorized float4)
// ---------------------------------------------------------------------------
__global__ __launch_bounds__(256) void reduce_h(const float* __restrict__ P,
    float* __restrict__ H) {
  int idx4 = blockIdx.x * 256 + threadIdx.x;
  const float4* P4 = (const float4*)P;
  float4 s = P4[idx4];
  #pragma unroll
  for (int ks = 1; ks < KSPLIT; ++ks) {
    float4 v = P4[(size_t)ks * (N_NODES * HID / 4) + idx4];
    s.x += v.x; s.y += v.y; s.z += v.z; s.w += v.w;
  }
  ((float4*)H)[idx4] = s;
}

// ---------------------------------------------------------------------------
// Kernel 3: Fst[0] = relu(H + b1) @ w2 + b2  (padded stride 8; pad col = 0)
// ---------------------------------------------------------------------------
__global__ __launch_bounds__(256) void mlp_out(const float* __restrict__ H,
    const float* __restrict__ b1, const float* __restrict__ w2,
    const float* __restrict__ b2, float* __restrict__ Fst0) {
  int t = blockIdx.x * blockDim.x + threadIdx.x;
  if (t >= N_NODES * FPAD) return;
  int row = t >> 3, c = t & 7;
  if (c == 7) { Fst0[t] = 0.0f; return; }
  float acc = b2[c];
  const float* h = H + (size_t)row * HID;
  #pragma unroll
  for (int k = 0; k < HID; ++k) {
    float hv = fmaxf(h[k] + b1[k], 0.0f);
    acc += hv * w2[k * OUT_DIM + c];
  }
  Fst0[t] = acc;
}

// ---------------------------------------------------------------------------
// Kernel 4: ALL 10 RUNG steps. Barrier v4 (round-6 post-mortem: the invariant
// ~13 us/step across rounds 4-6 = 256 same-line atomic RMWs serializing at the
// coherence point + 8B-granule bypass gathers).
//  - NO RMWs: each block STOREs its own padded flag line; block 0 wave 0 scans
//    all 256 flags and stores a per-step release word; others poll it (reads
//    of one line only).
//  - NO fences, NO bypass gathers: F state rotates through 10 distinct
//    buffers. Step k reads F[k] (plain cached float4 loads -- addresses never
//    cached before in this launch, so L2 miss -> L3 -> fresh data) and writes
//    F[k+1] via write-through stores.
// ---------------------------------------------------------------------------
__global__ __launch_bounds__(RT, 4) void rung_all(
    float* __restrict__ Fst,            // NSTEP buffers of N_NODES*FPAD
    float* __restrict__ out,
    const int* __restrict__ nbr, const int* __restrict__ cnt,
    const float* __restrict__ deg, const float* __restrict__ rsd,
    const float* __restrict__ lg0p, const float* __restrict__ rdp,
    int* __restrict__ flags,            // 256 flags, padded 16 ints (64B) each
    int* __restrict__ rel) {            // NSTEP release words, padded 16 ints
  int wave = threadIdx.x >> 6;
  int lane = threadIdx.x & 63;
  int i = blockIdx.x * (RT / 64) + wave;

  float r_  = 1.0f / (1.0f + expf(-rdp[0]));
  float lam = expf(lg0p[0]) * (1.0f / SCADA);          // lam_0; *= r_ each step

  float rsi = rsd[i];
  float Di  = deg[i];
  int   ci  = cnt[i];
  // hoisted neighbor state: lane covers slots lane and lane+64 (CAP=128)
  int   j0 = -1, j1 = -1;
  float rsj0 = 0.0f, rsj1 = 0.0f;
  if (lane < ci)      { j0 = nbr[(size_t)i * CAP + lane];      rsj0 = rsd[j0]; }
  if (lane + 64 < ci) { j1 = nbr[(size_t)i * CAP + lane + 64]; rsj1 = rsd[j1]; }

  float lf0[OUT_DIM];
  float myF[FPAD];
  {
    const float4* fp = (const float4*)(Fst + (size_t)i * FPAD);   // buffer 0
    float4 a0 = fp[0], a1 = fp[1];
    myF[0] = a0.x; myF[1] = a0.y; myF[2] = a0.z; myF[3] = a0.w;
    myF[4] = a1.x; myF[5] = a1.y; myF[6] = a1.z; myF[7] = a1.w;
    #pragma unroll
    for (int c = 0; c < OUT_DIM; ++c) lf0[c] = LAMBDA * myF[c];
  }

  for (int k = 0; k < NSTEP; ++k) {
    if (k) {
      __syncthreads();                  // drain vmcnt: F[k] stores are at L3
      if (blockIdx.x == 0) {
        if (threadIdx.x < 64) {         // detector wave: scan 256 flags
          int b1i = lane + 64, b2i = lane + 128, b3i = lane + 192;
          bool ok;
          do {
            int v0 = (lane == 0) ? k : ldflag(&flags[lane * 16]);
            int v1 = ldflag(&flags[b1i * 16]);
            int v2 = ldflag(&flags[b2i * 16]);
            int v3 = ldflag(&flags[b3i * 16]);
            ok = (v0 >= k) & (v1 >= k) & (v2 >= k) & (v3 >= k);
          } while (!__all(ok));
          if (lane == 0) stflag(&rel[k * 16], k);
        }
        __syncthreads();
      } else {
        if (threadIdx.x == 0) {
          stflag(&flags[blockIdx.x * 16], k);     // plain store: no contention
          while (ldflag(&rel[k * 16]) < k)        // read-only poll, one line
            __builtin_amdgcn_s_sleep(2);
        }
        __syncthreads();
      }
      asm volatile("" ::: "memory");    // no load hoisting above the poll
    }
    const float* Fin = Fst + (size_t)k * N_NODES * FPAD;

    float Fni[FPAD];
    #pragma unroll
    for (int c = 0; c < FPAD; ++c) Fni[c] = myF[c] * rsi;

    float s = 0.0f;
    float acc[OUT_DIM] = {0, 0, 0, 0, 0, 0, 0};
    #pragma unroll
    for (int half = 0; half < 2; ++half) {
      int   j   = half ? j1 : j0;
      float rsj = half ? rsj1 : rsj0;
      if (j >= 0) {
        const float4* fp = (const float4*)(Fin + (size_t)j * FPAD);
        float4 b0 = fp[0], b1v = fp[1];       // plain cached gathers
        float fj[FPAD] = {b0.x, b0.y, b0.z, b0.w, b1v.x, b1v.y, b1v.z, b1v.w};
        float d2 = 0.0f;
        #pragma unroll
        for (int c = 0; c < FPAD; ++c) {
          float df = Fni[c] - fj[c] * rsj;
          d2 += df * df;
        }
        float y = sqrtf(d2);
        float w;
        if (y <= lam)              w = 1.0f;
        else if (y <= SCADA * lam) w = (SCADA * lam - y) / ((SCADA - 1.0f) * fmaxf(y, 1e-12f));
        else                       w = 0.0f;
        if (w != w) w = 1.0f;      // NaN guard (matches reference)
        s += w;
        float wr = w * rsi * rsj;  // W_ij * A_tilde_ij
        #pragma unroll
        for (int c = 0; c < OUT_DIM; ++c) acc[c] += wr * fj[c];
      }
    }
    // butterfly reduction: ALL lanes end with the totals
    #pragma unroll
    for (int off = 1; off < 64; off <<= 1) {
      s += __shfl_xor(s, off);
      #pragma unroll
      for (int c = 0; c < OUT_DIM; ++c) acc[c] += __shfl_xor(acc[c], off);
    }
    float inv = 1.0f / (s / Di + LAMBDA);
    if (k == NSTEP - 1) {
      if (lane < OUT_DIM)
        out[(size_t)i * OUT_DIM + lane] = (acc[lane] + lf0[lane]) * inv;
    } else {
      #pragma unroll
      for (int c = 0; c < OUT_DIM; ++c) myF[c] = (acc[c] + lf0[c]) * inv;
      myF[7] = 0.0f;
      if (lane == 0) {                 // publish row to F[k+1] (write-through)
        float* op = Fst + (size_t)(k + 1) * N_NODES * FPAD + (size_t)i * FPAD;
        stcoh8(op,     myF[0], myF[1]);
        stcoh8(op + 2, myF[2], myF[3]);
        stcoh8(op + 4, myF[4], myF[5]);
        stcoh8(op + 6, myF[6], 0.0f);
      }
    }
    lam *= r_;
  }
}

// ---------------------------------------------------------------------------
extern "C" void kernel_launch(void* const* d_in, const int* in_sizes, int n_in,
                              void* d_out, int out_size, void* d_ws, size_t ws_size,
                              hipStream_t stream) {
  const float* A   = (const float*)d_in[0];
  const float* X   = (const float*)d_in[1];
  const float* w1  = (const float*)d_in[2];
  const float* b1  = (const float*)d_in[3];
  const float* w2  = (const float*)d_in[4];
  const float* b2  = (const float*)d_in[5];
  const float* lg0 = (const float*)d_in[6];
  const float* rd  = (const float*)d_in[7];
  float* out = (float*)d_out;

  char* w = (char*)d_ws;
  int*   nbr  = (int*)w;   w += (size_t)N_NODES * CAP * sizeof(int);
  int*   cnt  = (int*)w;   w += (size_t)N_NODES * sizeof(int);
  float* deg  = (float*)w; w += (size_t)N_NODES * sizeof(float);
  float* rsd  = (float*)w; w += (size_t)N_NODES * sizeof(float);
  float* P    = (float*)w; w += (size_t)KSPLIT * N_NODES * HID * sizeof(float);
  float* H    = (float*)w; w += (size_t)N_NODES * HID * sizeof(float);
  float* Fst  = (float*)w; w += (size_t)NSTEP * N_NODES * FPAD * sizeof(float);
  int*   flags = (int*)w;  w += 256 * 16 * sizeof(int);
  int*   rel   = (int*)w;  w += NSTEP * 16 * sizeof(int);

  hipMemsetAsync(flags, 0, (256 + NSTEP) * 16 * sizeof(int), stream);
  build_adj<<<N_NODES, 256, 0, stream>>>(A, nbr, cnt, deg, rsd);
  gemm1<<<dim3(N_NODES / BR, KSPLIT), 256, 0, stream>>>(X, w1, P);
  reduce_h<<<(N_NODES * HID / 4) / 256, 256, 0, stream>>>(P, H);
  mlp_out<<<(N_NODES * FPAD) / 256, 256, 0, stream>>>(H, b1, w2, b2, Fst);

  void* args[] = {&Fst, &out, &nbr, &cnt, &deg, &rsd,
                  (void*)&lg0, (void*)&rd, &flags, &rel};
  hipLaunchCooperativeKernel((const void*)rung_all, dim3(RB), dim3(RT),
                             args, 0, stream);
}